// Round 8
// baseline (3979.461 us; speedup 1.0000x reference)
//
#include <hip/hip_runtime.h>
#include <hip/hip_bf16.h>

#define BB 2
#define LL 2048
#define DD 1024
#define HH 16
#define DK 64
#define UU 40
#define BH (BB*HH)

typedef unsigned short u16;

__device__ inline float b2f_r8(u16 x) {
    union { unsigned short u; __hip_bfloat16 b; } c; c.u = x;
    return __bfloat162float(c.b);
}
// dual-dtype element load (fp32 or bf16 input), wave-uniform isF
__device__ inline float ldf_r8(const void* p, size_t i, int isF) {
    return isF ? ((const float*)p)[i] : b2f_r8(((const u16*)p)[i]);
}

// ---------------- K0: input dtype probe ----------------
__global__ __launch_bounds__(256) void detect_dtype_r8(const u16* __restrict__ q,
                                                       int* __restrict__ flag) {
    __shared__ float red[256];
    int tid = threadIdx.x;
    float mx = 0.f;
    for (int i = tid; i < 4096; i += 256) {
        float v = fabsf(b2f_r8(q[i]));
        if (!(v < 1e30f)) v = 1e38f;
        mx = fmaxf(mx, v);
    }
    red[tid] = mx; __syncthreads();
    for (int s = 128; s > 0; s >>= 1) {
        if (tid < s) red[tid] = fmaxf(red[tid], red[tid + s]);
        __syncthreads();
    }
    if (tid == 0) *flag = (red[0] > 1e20f) ? 1 : 0;
}

// ------------- K1: exact K projection, fp64 accum, hi/lo fp32 store -------------
__global__ __launch_bounds__(256) void kproj_exact_r8(
    const void* __restrict__ X, const void* __restrict__ W,
    const void* __restrict__ bias, float* __restrict__ Khi,
    float* __restrict__ Klo, const int* __restrict__ flag)
{
    __shared__ float sx[64 * 65];
    __shared__ float sw[64 * 65];
    int tid = threadIdx.x;
    int n0 = blockIdx.x * 64, f0 = blockIdx.y * 64;
    int isF = *flag;
    int ty = tid >> 4, tx = tid & 15;
    double acc[4][4] = {};
    for (int kc = 0; kc < 16; ++kc) {
        __syncthreads();
        for (int i = tid; i < 4096; i += 256) {
            int r = i >> 6, c = i & 63;
            sx[r * 65 + c] = ldf_r8(X, (size_t)(n0 + r) * DD + kc * 64 + c, isF);
            sw[r * 65 + c] = ldf_r8(W, (size_t)(f0 + r) * DD + kc * 64 + c, isF);
        }
        __syncthreads();
        for (int c = 0; c < 64; ++c) {
            double xa[4], wb[4];
#pragma unroll
            for (int a = 0; a < 4; ++a) xa[a] = (double)sx[(ty * 4 + a) * 65 + c];
#pragma unroll
            for (int q = 0; q < 4; ++q) wb[q] = (double)sw[(tx * 4 + q) * 65 + c];
#pragma unroll
            for (int a = 0; a < 4; ++a)
#pragma unroll
                for (int q = 0; q < 4; ++q) acc[a][q] += xa[a] * wb[q];
        }
    }
#pragma unroll
    for (int a = 0; a < 4; ++a) {
        int n = n0 + ty * 4 + a, b = n >> 11, l = n & (LL - 1);
#pragma unroll
        for (int q = 0; q < 4; ++q) {
            int f = f0 + tx * 4 + q, h = f >> 6, dk = f & 63;
            double v = acc[a][q] + (double)ldf_r8(bias, (size_t)f, isF);
            size_t o = ((size_t)(b * HH + h) * LL + l) * DK + dk;
            float hi = (float)v;
            Khi[o] = hi;
            Klo[o] = (float)(v - (double)hi);
        }
    }
}

// ---------------- K2: V projection, fp32 ----------------
__global__ __launch_bounds__(256) void proj_v_r8(
    const void* __restrict__ X, const void* __restrict__ W,
    const void* __restrict__ bias, float* __restrict__ out,
    const int* __restrict__ flag)
{
    __shared__ float sx[64 * 65];
    __shared__ float sw[64 * 65];
    int tid = threadIdx.x;
    int n0 = blockIdx.x * 64, f0 = blockIdx.y * 64;
    int isF = *flag;
    int ty = tid >> 4, tx = tid & 15;
    float acc[4][4] = {};
    for (int kc = 0; kc < 16; ++kc) {
        __syncthreads();
        for (int i = tid; i < 4096; i += 256) {
            int r = i >> 6, c = i & 63;
            sx[r * 65 + c] = ldf_r8(X, (size_t)(n0 + r) * DD + kc * 64 + c, isF);
            sw[r * 65 + c] = ldf_r8(W, (size_t)(f0 + r) * DD + kc * 64 + c, isF);
        }
        __syncthreads();
        for (int c = 0; c < 64; ++c) {
            float xa[4], wb[4];
#pragma unroll
            for (int a = 0; a < 4; ++a) xa[a] = sx[(ty * 4 + a) * 65 + c];
#pragma unroll
            for (int q = 0; q < 4; ++q) wb[q] = sw[(tx * 4 + q) * 65 + c];
#pragma unroll
            for (int a = 0; a < 4; ++a)
#pragma unroll
                for (int q = 0; q < 4; ++q) acc[a][q] = fmaf(xa[a], wb[q], acc[a][q]);
        }
    }
#pragma unroll
    for (int a = 0; a < 4; ++a) {
        int n = n0 + ty * 4 + a, b = n >> 11, l = n & (LL - 1);
#pragma unroll
        for (int q = 0; q < 4; ++q) {
            int f = f0 + tx * 4 + q, h = f >> 6, dk = f & 63;
            out[((size_t)(b * HH + h) * LL + l) * DK + dk] = acc[a][q] + ldf_r8(bias, (size_t)f, isF);
        }
    }
}

// ---- K3: fused exact Q-projection (16 rows) + M = rowmax - rowmean (fp64) ----
__global__ __launch_bounds__(256) void stats_exact_r8(
    const void* __restrict__ query, const void* __restrict__ Wq,
    const void* __restrict__ bq, const float* __restrict__ Khi,
    const float* __restrict__ Klo, double* __restrict__ Mv,
    const int* __restrict__ flag)
{
    __shared__ union {
        struct { float lw[64 * 65]; float lx[16 * 65]; } p1;
        double kd[32 * 65];
    } u;
    __shared__ double qd[16 * 65];
    __shared__ double rmA[256], rsA[256];
    int tid = threadIdx.x;
    int r0 = blockIdx.x * 16, bh = blockIdx.y;
    int b = bh >> 4, h = bh & 15;
    int isF = *flag;

    {
        int dk = tid & 63, rg = tid >> 6;
        double acc4[4] = {0, 0, 0, 0};
        for (int kc = 0; kc < 16; ++kc) {
            __syncthreads();
            for (int i = tid; i < 4096; i += 256) {
                int r = i >> 6, c = i & 63;
                u.p1.lw[r * 65 + c] = ldf_r8(Wq, (size_t)(h * 64 + r) * DD + kc * 64 + c, isF);
            }
            for (int i = tid; i < 1024; i += 256) {
                int r = i >> 6, c = i & 63;
                u.p1.lx[r * 65 + c] = ldf_r8(query, ((size_t)b * LL + r0 + r) * DD + kc * 64 + c, isF);
            }
            __syncthreads();
#pragma unroll
            for (int a = 0; a < 4; ++a) {
                int row = rg * 4 + a;
                double s = 0;
                for (int c = 0; c < 64; ++c)
                    s += (double)u.p1.lx[row * 65 + c] * (double)u.p1.lw[dk * 65 + c];
                acc4[a] += s;
            }
        }
        double bb = (double)ldf_r8(bq, (size_t)(h * 64 + dk), isF);
#pragma unroll
        for (int a = 0; a < 4; ++a) qd[(rg * 4 + a) * 65 + dk] = acc4[a] + bb;
    }

    double rm = -1e300, rs = 0.0;
    int row = tid & 15, kk = tid >> 4;
    for (int ch = 0; ch < 64; ++ch) {
        __syncthreads();
        for (int i = tid; i < 2048; i += 256) {
            int j = i >> 6, d = i & 63;
            size_t o = ((size_t)bh * LL + ch * 32 + j) * DK + d;
            u.kd[j * 65 + d] = (double)Khi[o] + (double)Klo[o];
        }
        __syncthreads();
#pragma unroll
        for (int t = 0; t < 2; ++t) {
            int j = kk + t * 16;
            double s = 0;
            for (int d = 0; d < 64; ++d) s += qd[row * 65 + d] * u.kd[j * 65 + d];
            rm = fmax(rm, s);
            rs += s;
        }
    }
    rmA[tid] = rm; rsA[tid] = rs;
    __syncthreads();
    for (int off = 128; off >= 16; off >>= 1) {
        if (tid < off) {
            rmA[tid] = fmax(rmA[tid], rmA[tid + off]);
            rsA[tid] += rsA[tid + off];
        }
        __syncthreads();
    }
    if (tid < 16)
        Mv[(size_t)bh * LL + r0 + tid] = rmA[tid] - rsA[tid] / (double)LL;
}

// ------- K4: exact top-40 per (b,h), DESCENDING (jax.lax.top_k), tie->low -------
__global__ __launch_bounds__(256) void topk_exact_r8(
    const double* __restrict__ Mv, int* __restrict__ sel)
{
    __shared__ double vals[LL];
    __shared__ double rv[256];
    __shared__ int ri[256];
    int bh = blockIdx.x, tid = threadIdx.x;
    for (int j = tid; j < LL; j += 256) vals[j] = Mv[(size_t)bh * LL + j];
    __syncthreads();
    for (int u = 0; u < UU; ++u) {
        double bv = -1e301; int bi = LL;
        for (int j = tid; j < LL; j += 256) {
            double v = vals[j];
            if (v > bv) { bv = v; bi = j; }
        }
        rv[tid] = bv; ri[tid] = bi;
        __syncthreads();
        for (int s = 128; s > 0; s >>= 1) {
            if (tid < s) {
                double ov = rv[tid + s]; int oi = ri[tid + s];
                if (ov > rv[tid] || (ov == rv[tid] && oi < ri[tid])) {
                    rv[tid] = ov; ri[tid] = oi;
                }
            }
            __syncthreads();
        }
        if (tid == 0) { sel[bh * UU + u] = ri[0]; vals[ri[0]] = -1e302; }
        __syncthreads();
    }
}

// ---- K5: exact q-row proj + scores + causal + softmax + probs + PV + attn ----
// OUTPUTS ARE FLOAT32 (reference output dtype is jnp.float32).
__global__ __launch_bounds__(256) void attn_out_r8(
    const void* __restrict__ query, const void* __restrict__ Wq,
    const void* __restrict__ bq, const float* __restrict__ Khi,
    const float* __restrict__ Klo, const float* __restrict__ Vf,
    const int* __restrict__ sel, float* __restrict__ attnOut,
    float* __restrict__ probsOut, const int* __restrict__ flag)
{
    __shared__ double qd[DK];
    __shared__ double redD[256];
    __shared__ float pl[LL];
    __shared__ float red[256];
    int u = blockIdx.x, bh = blockIdx.y, tid = threadIdx.x;
    int b = bh >> 4, h = bh & 15;
    int isF = *flag;
    int qpos = sel[bh * UU + u];

    {
        int dk = tid & 63, kg = tid >> 6;
        double s = 0;
        for (int k = kg * 256; k < kg * 256 + 256; ++k)
            s += (double)ldf_r8(query, ((size_t)b * LL + qpos) * DD + k, isF)
               * (double)ldf_r8(Wq, (size_t)(h * 64 + dk) * DD + k, isF);
        redD[tid] = s; __syncthreads();
        if (tid < 64) {
            double t = redD[tid] + redD[tid + 64] + redD[tid + 128] + redD[tid + 192];
            qd[tid] = t + (double)ldf_r8(bq, (size_t)(h * 64 + tid), isF);
        }
        __syncthreads();
    }

    float sloc[8];
    float lmax = -INFINITY;
#pragma unroll
    for (int c = 0; c < 8; ++c) {
        int l = c * 256 + tid;
        size_t o = ((size_t)bh * LL + l) * DK;
        double s = 0;
        for (int d = 0; d < 64; ++d)
            s += qd[d] * ((double)Khi[o + d] + (double)Klo[o + d]);
        float sf = (float)(s * 0.125);
        if (l > qpos) sf -= 1e9f;
        sloc[c] = sf;
        lmax = fmaxf(lmax, sf);
    }
    red[tid] = lmax; __syncthreads();
    for (int s2 = 128; s2 > 0; s2 >>= 1) {
        if (tid < s2) red[tid] = fmaxf(red[tid], red[tid + s2]);
        __syncthreads();
    }
    float mval = red[0];
    __syncthreads();
    float lsum = 0.f;
#pragma unroll
    for (int c = 0; c < 8; ++c) { sloc[c] = expf(sloc[c] - mval); lsum += sloc[c]; }
    red[tid] = lsum; __syncthreads();
    for (int s2 = 128; s2 > 0; s2 >>= 1) {
        if (tid < s2) red[tid] += red[tid + s2];
        __syncthreads();
    }
    float inv = 1.0f / red[0];
    size_t rowo = ((size_t)bh * UU + u) * LL;
#pragma unroll
    for (int c = 0; c < 8; ++c) {
        int l = c * 256 + tid;
        float p = sloc[c] * inv;
        pl[l] = p;
        probsOut[rowo + l] = p;           // fp32 store
    }
    __syncthreads();

    int dk = tid & 63, c4 = tid >> 6;
    const float* vb = Vf + (size_t)bh * LL * DK;
    float acc = 0.f;
    for (int l = c4 * (LL / 4); l < (c4 + 1) * (LL / 4); ++l)
        acc = fmaf(pl[l], vb[(size_t)l * DK + dk], acc);
    red[tid] = acc; __syncthreads();
    if (tid < 64) {
        float s2 = red[tid] + red[tid + 64] + red[tid + 128] + red[tid + 192];
        attnOut[((size_t)b * UU + u) * DD + h * DK + dk] = s2;   // fp32 store
    }
}

extern "C" void kernel_launch(void* const* d_in, const int* in_sizes, int n_in,
                              void* d_out, int out_size, void* d_ws, size_t ws_size,
                              hipStream_t stream) {
    (void)in_sizes; (void)n_in; (void)out_size; (void)ws_size;
    const void* query = d_in[0];
    const void* key   = d_in[1];
    const void* value = d_in[2];
    const void* Wq    = d_in[3];
    const void* bq    = d_in[4];
    const void* Wk    = d_in[5];
    const void* bk    = d_in[6];
    const void* Wv    = d_in[7];
    const void* bv    = d_in[8];

    char* w = (char*)d_ws;
    const size_t NE = (size_t)BB * HH * LL * DK;   // 4,194,304
    float* Khi = (float*)w;  w += NE * 4;
    float* Klo = (float*)w;  w += NE * 4;
    float* Vf  = (float*)w;  w += NE * 4;
    double* Mv = (double*)w; w += (size_t)BH * LL * 8;
    int* sel   = (int*)w;    w += (size_t)BH * UU * 4;
    int* flag  = (int*)w;    w += 64;

    float* attnOut  = (float*)d_out;                       // FP32 outputs
    float* probsOut = attnOut + (size_t)BB * UU * DD;

    dim3 blk(256);
    detect_dtype_r8<<<1, blk, 0, stream>>>((const u16*)query, flag);
    kproj_exact_r8<<<dim3(64, 16), blk, 0, stream>>>(key, Wk, bk, Khi, Klo, flag);
    proj_v_r8<<<dim3(64, 16), blk, 0, stream>>>(value, Wv, bv, Vf, flag);
    stats_exact_r8<<<dim3(128, 32), blk, 0, stream>>>(query, Wq, bq, Khi, Klo, Mv, flag);
    topk_exact_r8<<<32, blk, 0, stream>>>(Mv, sel);
    attn_out_r8<<<dim3(UU, 32), blk, 0, stream>>>(query, Wq, bq, Khi, Klo, Vf,
                                                  sel, attnOut, probsOut, flag);
}